// Round 6
// baseline (663.210 us; speedup 1.0000x reference)
//
#include <hip/hip_runtime.h>
#include <hip/hip_bf16.h>

#define HD __device__ __forceinline__
typedef unsigned short u16;
typedef __attribute__((ext_vector_type(8))) short bf16x8;
typedef __attribute__((ext_vector_type(4))) float f32x4;

// round-to-nearest-even fp32 -> bf16 bits
HD u16 f2b(float f){
  unsigned u = __float_as_uint(f);
  unsigned r = (u + 0x7fffu + ((u>>16)&1u)) >> 16;
  return (u16)r;
}
HD float b2f(short s){ return __uint_as_float(((unsigned)(u16)s)<<16); }

// ---------------- CSR build ----------------
__global__ void k_count(const int* __restrict__ dst, const float* __restrict__ ea,
                        int* cnt, float* easum, int E){
  int e = blockIdx.x*blockDim.x + threadIdx.x;
  if (e>=E) return;
  int d = dst[e];
  atomicAdd(&cnt[d],1);
  atomicAdd(&easum[d], ea[e]);
}

// two-level scan, one block
__global__ __launch_bounds__(1024) void k_scan(const int* __restrict__ cnt, int* offs, int N){
  __shared__ int lds[1024];
  const int chunk = (N + 1023)/1024;
  const int b = threadIdx.x*chunk;
  int s = 0;
  for (int i=0;i<chunk;++i){ int idx=b+i; if (idx<N) s += cnt[idx]; }
  lds[threadIdx.x] = s;
  __syncthreads();
  #pragma unroll
  for (int off=1; off<1024; off<<=1){
    int t = (threadIdx.x>=(unsigned)off)? lds[threadIdx.x-off] : 0;
    __syncthreads();
    lds[threadIdx.x] += t;
    __syncthreads();
  }
  int excl = lds[threadIdx.x] - s;
  for (int i=0;i<chunk;++i){
    int idx=b+i;
    if (idx<N){ offs[idx] = excl; excl += cnt[idx]; }
  }
  if (threadIdx.x==1023) offs[N] = lds[1023];
}

__global__ void k_scatter(const int* __restrict__ src, const int* __restrict__ dst,
                          const float* __restrict__ ea, const int* __restrict__ offs,
                          int* fill, int* srcs, float* eas, int E){
  int e = blockIdx.x*blockDim.x + threadIdx.x;
  if (e>=E) return;
  int d = dst[e];
  int p = offs[d] + atomicAdd(&fill[d],1);
  srcs[p] = src[e];
  eas[p]  = ea[e];
}

// merged: loop-attr (blocks [0,nbLoop)) + wedot (blocks nbLoop, nbLoop+1)
__global__ __launch_bounds__(512) void k_prep_small(
    const int* __restrict__ cnt, const float* __restrict__ easum, float* la, int N,
    const float* __restrict__ We1, const float* __restrict__ ae1,
    const float* __restrict__ We2, const float* __restrict__ ae2,
    float* wedot, int nbLoop){
  int bx = blockIdx.x;
  if (bx < nbLoop){
    int n = bx*512 + threadIdx.x;
    if (n<N) la[n] = easum[n] / fmaxf((float)cnt[n], 1.f);
    return;
  }
  int which = bx - nbLoop;
  const float* We = which? We2 : We1;
  const float* ae = which? ae2 : ae1;
  int hh = threadIdx.x>>6, lane = threadIdx.x&63;
  float p = We[hh*64+lane]*ae[hh*64+lane];
  #pragma unroll
  for (int o=32;o;o>>=1) p += __shfl_down(p,o);
  if (lane==0) wedot[which*8+hh] = p;
}

// merged: x cast (blocks [0,nbCast)) + W1 transpose (next nbW1) + W2 transpose
__global__ __launch_bounds__(256) void k_prep_cast(
    const float* __restrict__ x, u16* __restrict__ xb, int total4,
    const float* __restrict__ W1, u16* __restrict__ W1t,
    const float* __restrict__ W2, u16* __restrict__ W2t,
    int nbCast, int nbW1){
  __shared__ float T[64][65];
  int bx = blockIdx.x;
  if (bx < nbCast){
    int i = bx*256 + threadIdx.x;
    if (i<total4){
      float4 v = *(const float4*)(x + (size_t)i*4);
      ushort4 o; o.x=f2b(v.x); o.y=f2b(v.y); o.z=f2b(v.z); o.w=f2b(v.w);
      *(ushort4*)(xb + (size_t)i*4) = o;
    }
    return;
  }
  const float* W; u16* Wt; int K, Nn, t;
  if (bx < nbCast + nbW1){ t = bx - nbCast;        W = W1; Wt = W1t; K = 128; Nn = 512; }
  else                   { t = bx - nbCast - nbW1; W = W2; Wt = W2t; K = 512; Nn = 512; }
  int nt = Nn/64;
  int k0 = (t/nt)*64, n0 = (t%nt)*64;
  #pragma unroll
  for (int i=0;i<16;++i){
    int id = i*256 + threadIdx.x;
    int r = id>>6, c = id&63;
    T[r][c] = W[(size_t)(k0+r)*Nn + n0 + c];
  }
  __syncthreads();
  #pragma unroll
  for (int i=0;i<16;++i){
    int id = i*256 + threadIdx.x;
    int rr = id>>6, cc = id&63;
    Wt[(size_t)(n0+rr)*K + k0 + cc] = f2b(T[cc][rr]);
  }
}

// ---------------- bf16 MFMA GEMM: Cb[M,N] = A[M,K] @ Bt[N,K]^T (bf16 out) ---
// tile 128x128, BK=32, 256 threads = 4 waves in 2x2 (wave tile 64x64)
__global__ __launch_bounds__(256) void k_gemm_mfma(
    const u16* __restrict__ A, const u16* __restrict__ Bt,
    u16* __restrict__ Cb, int M, int N, int K){
  __shared__ char lds[256*80];   // A:128 rows, B:128 rows; stride 80B (conflict-free)
  char* As = lds;
  char* Bs = lds + 128*80;
  const int tid = threadIdx.x;
  const int lane = tid & 63, w = tid >> 6;
  const int wr = w >> 1, wc = w & 1;
  const int l15 = lane & 15, l4 = lane >> 4;
  const int m0 = blockIdx.y*128, n0 = blockIdx.x*128;

  f32x4 acc[4][4] = {};
  int aoff[4], boff[4];
  #pragma unroll
  for (int i=0;i<4;++i) aoff[i] = (wr*64 + i*16 + l15)*80 + l4*16;
  #pragma unroll
  for (int j=0;j<4;++j) boff[j] = (wc*64 + j*16 + l15)*80 + l4*16;

  for (int k0=0; k0<K; k0+=32){
    // stage A: 128 rows x 64B = 512 chunks of 16B, 2 per thread
    #pragma unroll
    for (int i=0;i<2;++i){
      int cid = tid*2+i;
      int r = cid>>2, c = cid&3;
      int row = m0 + r;
      float4 v = make_float4(0.f,0.f,0.f,0.f);
      if (row < M) v = *(const float4*)(A + (size_t)row*K + k0 + c*8);
      *(float4*)(As + r*80 + c*16) = v;
    }
    // stage B: 128 rows x 64B = 512 chunks, 2 per thread (N multiple of 128)
    #pragma unroll
    for (int i=0;i<2;++i){
      int cid = tid*2+i;
      int r = cid>>2, c = cid&3;
      float4 v = *(const float4*)(Bt + (size_t)(n0+r)*K + k0 + c*8);
      *(float4*)(Bs + r*80 + c*16) = v;
    }
    __syncthreads();
    bf16x8 a[4], b[4];
    #pragma unroll
    for (int i=0;i<4;++i) a[i] = *reinterpret_cast<const bf16x8*>(As + aoff[i]);
    #pragma unroll
    for (int j=0;j<4;++j) b[j] = *reinterpret_cast<const bf16x8*>(Bs + boff[j]);
    #pragma unroll
    for (int i=0;i<4;++i)
      #pragma unroll
      for (int j=0;j<4;++j)
        acc[i][j] = __builtin_amdgcn_mfma_f32_16x16x32_bf16(a[i], b[j], acc[i][j], 0,0,0);
    __syncthreads();
  }
  // epilogue: C[row][col], row=(lane>>4)*4+reg, col=lane&15
  #pragma unroll
  for (int i=0;i<4;++i){
    #pragma unroll
    for (int j=0;j<4;++j){
      #pragma unroll
      for (int r=0;r<4;++r){
        int row = m0 + wr*64 + i*16 + l4*4 + r;
        int col = n0 + wc*64 + j*16 + l15;
        if (row < M) Cb[(size_t)row*N + col] = f2b(acc[i][j][r]);
      }
    }
  }
}

// alpha_src[n,h], alpha_dst[n,h] from bf16 h; one wave per node (4/block)
__global__ __launch_bounds__(256) void k_alpha_nodes(const u16* __restrict__ hb,
    const float* __restrict__ a_s, const float* __restrict__ a_d,
    float* asrc, float* adst, int N){
  int n = blockIdx.x*4 + (threadIdx.x>>6);
  if (n>=N) return;
  int lane = threadIdx.x&63;
  int c0 = lane*8;
  bf16x8 v = *(const bf16x8*)(hb + (size_t)n*512 + c0);
  float s = 0.f, d = 0.f;
  #pragma unroll
  for (int j=0;j<8;++j){
    float f = b2f(v[j]);
    s = fmaf(f, a_s[c0+j], s);
    d = fmaf(f, a_d[c0+j], d);
  }
  #pragma unroll
  for (int o=1;o<8;o<<=1){ s += __shfl_xor(s,o); d += __shfl_xor(d,o); }
  if ((lane&7)==0){ int hh = lane>>3; asrc[n*8+hh]=s; adst[n*8+hh]=d; }
}

// ---------------- FUSED per-node softmax + aggregate ----------------
// One wave owns node n end-to-end.
// Phase 1/2 lane roles: (hh=lane&7, esub=lane>>3). Phase 3: lane covers
// channels lane*8..lane*8+7, head ahh=lane>>3. exn is same-kernel scratch.
__global__ __launch_bounds__(256) void k_softagg(const u16* __restrict__ hb,
    const int* __restrict__ srcs, const float* __restrict__ eas,
    const int* __restrict__ offs,
    const float* __restrict__ asrc, const float* __restrict__ adst,
    const float* __restrict__ wedot, const float* __restrict__ la,
    const float* __restrict__ bias, float* __restrict__ exn,
    u16* __restrict__ outb,
    int N, int relu_flag, int self_flag){
  int n = blockIdx.x*4 + (threadIdx.x>>6);
  if (n>=N) return;
  int lane = threadIdx.x&63;
  int hh = lane&7, esub = lane>>3;
  int beg = offs[n], end = offs[n+1];
  float wd = wedot[hh];
  float adn = adst[n*8+hh];

  // pass 1: alpha -> exn (raw), running max
  float mx = -1e30f;
  for (int p0=beg; p0<end; p0+=8){
    int p = p0 + esub;
    if (p<end){
      int s = srcs[p];
      float a = asrc[s*8+hh] + adn + eas[p]*wd;
      a = a>0.f ? a : 0.2f*a;
      exn[(size_t)p*8+hh] = a;
      mx = fmaxf(mx, a);
    }
  }
  float aselfa = 0.f;
  if (self_flag){
    float a = asrc[n*8+hh] + adn + la[n]*wd;
    aselfa = a>0.f ? a : 0.2f*a;
    mx = fmaxf(mx, aselfa);      // same per head across esub; safe pre-reduce
  }
  mx = fmaxf(mx, __shfl_xor(mx, 8));
  mx = fmaxf(mx, __shfl_xor(mx, 16));
  mx = fmaxf(mx, __shfl_xor(mx, 32));

  // pass 2: exp + sum (stores unnormalized exp back to exn)
  float sum = 0.f;
  for (int p0=beg; p0<end; p0+=8){
    int p = p0 + esub;
    if (p<end){
      float x = __expf(exn[(size_t)p*8+hh] - mx);
      exn[(size_t)p*8+hh] = x;
      sum += x;
    }
  }
  float xs = self_flag ? __expf(aselfa - mx) : 0.f;
  if (esub==0) sum += xs;
  sum += __shfl_xor(sum, 8);
  sum += __shfl_xor(sum, 16);
  sum += __shfl_xor(sum, 32);
  float invv = 1.f/(sum + 1e-16f);

  // make this wave's exn stores visible to cross-lane reads below
  __threadfence();

  // pass 3: aggregate; lane role switches to channel-slot
  int ahh = lane>>3;                    // head for this lane's channels
  float iv = __shfl(invv, ahh);         // lane ahh (esub=0,hh=ahh) holds it
  float es = __shfl(xs,   ahh);
  int c0 = lane*8;
  float acc[8] = {};
  int p = beg;
  for (; p+2<=end; p+=2){
    int s0 = srcs[p], s1 = srcs[p+1];
    float e0 = exn[(size_t)p*8 + ahh];
    float e1 = exn[(size_t)(p+1)*8 + ahh];
    bf16x8 v0 = *(const bf16x8*)(hb + (size_t)s0*512 + c0);
    bf16x8 v1 = *(const bf16x8*)(hb + (size_t)s1*512 + c0);
    #pragma unroll
    for (int j=0;j<8;++j)
      acc[j] = fmaf(e0, b2f(v0[j]), fmaf(e1, b2f(v1[j]), acc[j]));
  }
  if (p<end){
    int s0 = srcs[p];
    float e0 = exn[(size_t)p*8 + ahh];
    bf16x8 v0 = *(const bf16x8*)(hb + (size_t)s0*512 + c0);
    #pragma unroll
    for (int j=0;j<8;++j) acc[j] = fmaf(e0, b2f(v0[j]), acc[j]);
  }
  if (self_flag){
    bf16x8 v = *(const bf16x8*)(hb + (size_t)n*512 + c0);
    #pragma unroll
    for (int j=0;j<8;++j) acc[j] = fmaf(es, b2f(v[j]), acc[j]);
  }
  bf16x8 ov;
  #pragma unroll
  for (int j=0;j<8;++j){
    float val = acc[j]*iv + bias[c0+j];
    if (relu_flag) val = fmaxf(val, 0.f);
    ov[j] = (short)f2b(val);
  }
  *(bf16x8*)(outb + (size_t)n*512 + c0) = ov;
}

// column mean over bf16 rows: 512 threads (one per channel), 16 rows/block
__global__ __launch_bounds__(512) void k_colmean(const u16* __restrict__ out2b,
                          float* __restrict__ o, int N, float invN){
  int c = threadIdx.x;
  int n0 = blockIdx.x*16;
  int nend = min(n0+16, N);
  float s = 0.f;
  for (int n=n0;n<nend;++n) s += b2f(out2b[(size_t)n*512 + c]);
  atomicAdd(&o[c], s*invN);
}

extern "C" void kernel_launch(void* const* d_in, const int* in_sizes, int n_in,
                              void* d_out, int out_size, void* d_ws, size_t ws_size,
                              hipStream_t stream){
  const float* x   = (const float*)d_in[0];
  const int* eidx  = (const int*)d_in[1];
  const float* ea  = (const float*)d_in[2];
  const float* W1  = (const float*)d_in[3];
  const float* We1 = (const float*)d_in[4];
  const float* as1 = (const float*)d_in[5];
  const float* ad1 = (const float*)d_in[6];
  const float* ae1 = (const float*)d_in[7];
  const float* b1  = (const float*)d_in[8];
  const float* W2  = (const float*)d_in[9];
  const float* We2 = (const float*)d_in[10];
  const float* as2 = (const float*)d_in[11];
  const float* ad2 = (const float*)d_in[12];
  const float* ae2 = (const float*)d_in[13];
  const float* b2  = (const float*)d_in[14];
  float* outp = (float*)d_out;

  const int FIN = 128, D1 = 512;
  const int N = in_sizes[0]/FIN;
  const int E = in_sizes[1]/2;
  const int* srcA = eidx;
  const int* dstA = eidx + E;

  char* ws = (char*)d_ws;
  size_t o = 0;
  auto alloc = [&](size_t bytes)->void*{
    void* p = ws + o; o = (o + bytes + 255) & ~(size_t)255; return p;
  };
  u16*   hb1   = (u16*)  alloc((size_t)N*D1*2);   // layer1 features, bf16
  u16*   hb2   = (u16*)  alloc((size_t)N*D1*2);   // layer2 features, bf16
  u16*   out1rb= (u16*)  alloc((size_t)N*D1*2);   // relu(layer1 out), bf16
  u16*   out2b = (u16*)  alloc((size_t)N*D1*2);   // layer2 out, bf16
  u16*   xb    = (u16*)  alloc((size_t)N*FIN*2);
  u16*   W1t   = (u16*)  alloc((size_t)D1*FIN*2); // [512][128]
  u16*   W2t   = (u16*)  alloc((size_t)D1*D1*2);  // [512][512]
  float* exn   = (float*)alloc((size_t)E*8*4);    // per-edge scratch
  int*   srcs  = (int*)  alloc((size_t)E*4);
  float* eas   = (float*)alloc((size_t)E*4);
  int*   offs  = (int*)  alloc((size_t)(N+1)*4);
  size_t zbeg = o;
  int*   cnt   = (int*)  alloc((size_t)N*4);
  int*   fill  = (int*)  alloc((size_t)N*4);
  float* easum = (float*)alloc((size_t)N*4);
  size_t zend = o;
  float* asrc  = (float*)alloc((size_t)N*8*4);
  float* adst  = (float*)alloc((size_t)N*8*4);
  float* la    = (float*)alloc((size_t)N*4);
  float* wedot = (float*)alloc(64);
  (void)ws_size; (void)n_in;

  hipMemsetAsync(ws + zbeg, 0, zend - zbeg, stream);
  hipMemsetAsync(d_out, 0, (size_t)out_size*sizeof(float), stream);

  dim3 b256(256);
  int ge = (E+255)/256;
  int gn4 = (N+3)/4;

  // CSR build + prep (merged kernels)
  k_count   <<<ge, b256, 0, stream>>>(dstA, ea, cnt, easum, E);
  k_scan    <<<1, 1024, 0, stream>>>(cnt, offs, N);
  k_scatter <<<ge, b256, 0, stream>>>(srcA, dstA, ea, offs, fill, srcs, eas, E);
  {
    int nbLoop = (N+511)/512;
    k_prep_small<<<nbLoop+2, 512, 0, stream>>>(cnt, easum, la, N,
                                               We1, ae1, We2, ae2, wedot, nbLoop);
    int total4 = N*FIN/4;
    int nbCast = (total4+255)/256;
    int nbW1 = (FIN/64)*(D1/64);          // 16
    int nbW2 = (D1/64)*(D1/64);           // 64
    k_prep_cast<<<nbCast+nbW1+nbW2, b256, 0, stream>>>(x, xb, total4,
                                                       W1, W1t, W2, W2t, nbCast, nbW1);
  }

  // ---- layer 1 (no self loops) ----
  k_gemm_mfma<<<dim3(D1/128, (N+127)/128), b256, 0, stream>>>(xb, W1t, hb1, N, D1, FIN);
  k_alpha_nodes<<<gn4, b256, 0, stream>>>(hb1, as1, ad1, asrc, adst, N);
  k_softagg<<<gn4, b256, 0, stream>>>(hb1, srcs, eas, offs, asrc, adst, wedot, la,
                                      b1, exn, out1rb, N, 1, 0);

  // ---- layer 2 (self loops, fill='mean') ----
  k_gemm_mfma<<<dim3(D1/128, (N+127)/128), b256, 0, stream>>>(out1rb, W2t, hb2, N, D1, D1);
  k_alpha_nodes<<<gn4, b256, 0, stream>>>(hb2, as2, ad2, asrc, adst, N);
  k_softagg<<<gn4, b256, 0, stream>>>(hb2, srcs, eas, offs, asrc, adst, wedot+8, la,
                                      b2, exn, out2b, N, 0, 1);

  // ---- mean over nodes ----
  k_colmean<<<(N+15)/16, 512, 0, stream>>>(out2b, outp, N, 1.0f/(float)N);
}

// Round 7
// 187.555 us; speedup vs baseline: 3.5361x; 3.5361x over previous
//
#include <hip/hip_runtime.h>
#include <hip/hip_bf16.h>

#define HD __device__ __forceinline__
typedef unsigned short u16;
typedef __attribute__((ext_vector_type(8))) short bf16x8;
typedef __attribute__((ext_vector_type(4))) float f32x4;

// round-to-nearest-even fp32 -> bf16 bits
HD u16 f2b(float f){
  unsigned u = __float_as_uint(f);
  unsigned r = (u + 0x7fffu + ((u>>16)&1u)) >> 16;
  return (u16)r;
}
HD float b2f(short s){ return __uint_as_float(((unsigned)(u16)s)<<16); }

// ---------------- CSR build ----------------
__global__ void k_count(const int* __restrict__ dst, const float* __restrict__ ea,
                        int* cnt, float* easum, int E){
  int e = blockIdx.x*blockDim.x + threadIdx.x;
  if (e>=E) return;
  int d = dst[e];
  atomicAdd(&cnt[d],1);
  atomicAdd(&easum[d], ea[e]);
}

// two-level scan, one block
__global__ __launch_bounds__(1024) void k_scan(const int* __restrict__ cnt, int* offs, int N){
  __shared__ int lds[1024];
  const int chunk = (N + 1023)/1024;
  const int b = threadIdx.x*chunk;
  int s = 0;
  for (int i=0;i<chunk;++i){ int idx=b+i; if (idx<N) s += cnt[idx]; }
  lds[threadIdx.x] = s;
  __syncthreads();
  #pragma unroll
  for (int off=1; off<1024; off<<=1){
    int t = (threadIdx.x>=(unsigned)off)? lds[threadIdx.x-off] : 0;
    __syncthreads();
    lds[threadIdx.x] += t;
    __syncthreads();
  }
  int excl = lds[threadIdx.x] - s;
  for (int i=0;i<chunk;++i){
    int idx=b+i;
    if (idx<N){ offs[idx] = excl; excl += cnt[idx]; }
  }
  if (threadIdx.x==1023) offs[N] = lds[1023];
}

__global__ void k_scatter(const int* __restrict__ src, const int* __restrict__ dst,
                          const float* __restrict__ ea, const int* __restrict__ offs,
                          int* fill, int* srcs, float* eas, int E){
  int e = blockIdx.x*blockDim.x + threadIdx.x;
  if (e>=E) return;
  int d = dst[e];
  int p = offs[d] + atomicAdd(&fill[d],1);
  srcs[p] = src[e];
  eas[p]  = ea[e];
}

// merged: loop-attr (blocks [0,nbLoop)) + wedot (blocks nbLoop, nbLoop+1)
__global__ __launch_bounds__(512) void k_prep_small(
    const int* __restrict__ cnt, const float* __restrict__ easum, float* la, int N,
    const float* __restrict__ We1, const float* __restrict__ ae1,
    const float* __restrict__ We2, const float* __restrict__ ae2,
    float* wedot, int nbLoop){
  int bx = blockIdx.x;
  if (bx < nbLoop){
    int n = bx*512 + threadIdx.x;
    if (n<N) la[n] = easum[n] / fmaxf((float)cnt[n], 1.f);
    return;
  }
  int which = bx - nbLoop;
  const float* We = which? We2 : We1;
  const float* ae = which? ae2 : ae1;
  int hh = threadIdx.x>>6, lane = threadIdx.x&63;
  float p = We[hh*64+lane]*ae[hh*64+lane];
  #pragma unroll
  for (int o=32;o;o>>=1) p += __shfl_down(p,o);
  if (lane==0) wedot[which*8+hh] = p;
}

// merged: x cast (blocks [0,nbCast)) + W1 transpose (next nbW1) + W2 transpose
__global__ __launch_bounds__(256) void k_prep_cast(
    const float* __restrict__ x, u16* __restrict__ xb, int total4,
    const float* __restrict__ W1, u16* __restrict__ W1t,
    const float* __restrict__ W2, u16* __restrict__ W2t,
    int nbCast, int nbW1){
  __shared__ float T[64][65];
  int bx = blockIdx.x;
  if (bx < nbCast){
    int i = bx*256 + threadIdx.x;
    if (i<total4){
      float4 v = *(const float4*)(x + (size_t)i*4);
      ushort4 o; o.x=f2b(v.x); o.y=f2b(v.y); o.z=f2b(v.z); o.w=f2b(v.w);
      *(ushort4*)(xb + (size_t)i*4) = o;
    }
    return;
  }
  const float* W; u16* Wt; int K, Nn, t;
  if (bx < nbCast + nbW1){ t = bx - nbCast;        W = W1; Wt = W1t; K = 128; Nn = 512; }
  else                   { t = bx - nbCast - nbW1; W = W2; Wt = W2t; K = 512; Nn = 512; }
  int nt = Nn/64;
  int k0 = (t/nt)*64, n0 = (t%nt)*64;
  #pragma unroll
  for (int i=0;i<16;++i){
    int id = i*256 + threadIdx.x;
    int r = id>>6, c = id&63;
    T[r][c] = W[(size_t)(k0+r)*Nn + n0 + c];
  }
  __syncthreads();
  #pragma unroll
  for (int i=0;i<16;++i){
    int id = i*256 + threadIdx.x;
    int rr = id>>6, cc = id&63;
    Wt[(size_t)(n0+rr)*K + k0 + cc] = f2b(T[cc][rr]);
  }
}

// ---------------- bf16 MFMA GEMM: Cb[M,N] = A[M,K] @ Bt[N,K]^T (bf16 out) ---
// tile 128x128, BK=32, 256 threads = 4 waves in 2x2 (wave tile 64x64)
__global__ __launch_bounds__(256) void k_gemm_mfma(
    const u16* __restrict__ A, const u16* __restrict__ Bt,
    u16* __restrict__ Cb, int M, int N, int K){
  __shared__ char lds[256*80];   // A:128 rows, B:128 rows; stride 80B (conflict-free)
  char* As = lds;
  char* Bs = lds + 128*80;
  const int tid = threadIdx.x;
  const int lane = tid & 63, w = tid >> 6;
  const int wr = w >> 1, wc = w & 1;
  const int l15 = lane & 15, l4 = lane >> 4;
  const int m0 = blockIdx.y*128, n0 = blockIdx.x*128;

  f32x4 acc[4][4] = {};
  int aoff[4], boff[4];
  #pragma unroll
  for (int i=0;i<4;++i) aoff[i] = (wr*64 + i*16 + l15)*80 + l4*16;
  #pragma unroll
  for (int j=0;j<4;++j) boff[j] = (wc*64 + j*16 + l15)*80 + l4*16;

  for (int k0=0; k0<K; k0+=32){
    #pragma unroll
    for (int i=0;i<2;++i){
      int cid = tid*2+i;
      int r = cid>>2, c = cid&3;
      int row = m0 + r;
      float4 v = make_float4(0.f,0.f,0.f,0.f);
      if (row < M) v = *(const float4*)(A + (size_t)row*K + k0 + c*8);
      *(float4*)(As + r*80 + c*16) = v;
    }
    #pragma unroll
    for (int i=0;i<2;++i){
      int cid = tid*2+i;
      int r = cid>>2, c = cid&3;
      float4 v = *(const float4*)(Bt + (size_t)(n0+r)*K + k0 + c*8);
      *(float4*)(Bs + r*80 + c*16) = v;
    }
    __syncthreads();
    bf16x8 a[4], b[4];
    #pragma unroll
    for (int i=0;i<4;++i) a[i] = *reinterpret_cast<const bf16x8*>(As + aoff[i]);
    #pragma unroll
    for (int j=0;j<4;++j) b[j] = *reinterpret_cast<const bf16x8*>(Bs + boff[j]);
    #pragma unroll
    for (int i=0;i<4;++i)
      #pragma unroll
      for (int j=0;j<4;++j)
        acc[i][j] = __builtin_amdgcn_mfma_f32_16x16x32_bf16(a[i], b[j], acc[i][j], 0,0,0);
    __syncthreads();
  }
  #pragma unroll
  for (int i=0;i<4;++i){
    #pragma unroll
    for (int j=0;j<4;++j){
      #pragma unroll
      for (int r=0;r<4;++r){
        int row = m0 + wr*64 + i*16 + l4*4 + r;
        int col = n0 + wc*64 + j*16 + l15;
        if (row < M) Cb[(size_t)row*N + col] = f2b(acc[i][j][r]);
      }
    }
  }
}

// alpha_src[n,h], alpha_dst[n,h] from bf16 h; one wave per node (4/block)
__global__ __launch_bounds__(256) void k_alpha_nodes(const u16* __restrict__ hb,
    const float* __restrict__ a_s, const float* __restrict__ a_d,
    float* asrc, float* adst, int N){
  int n = blockIdx.x*4 + (threadIdx.x>>6);
  if (n>=N) return;
  int lane = threadIdx.x&63;
  int c0 = lane*8;
  bf16x8 v = *(const bf16x8*)(hb + (size_t)n*512 + c0);
  float s = 0.f, d = 0.f;
  #pragma unroll
  for (int j=0;j<8;++j){
    float f = b2f(v[j]);
    s = fmaf(f, a_s[c0+j], s);
    d = fmaf(f, a_d[c0+j], d);
  }
  #pragma unroll
  for (int o=1;o<8;o<<=1){ s += __shfl_xor(s,o); d += __shfl_xor(d,o); }
  if ((lane&7)==0){ int hh = lane>>3; asrc[n*8+hh]=s; adst[n*8+hh]=d; }
}

// ---------------- single-pass online-softmax aggregate ----------------
// One wave per node. Producer role (hh=lane&7, esub=lane>>3) computes alpha
// for one (edge,head); consumer role (head ahh=lane>>3, channels lane*8..+8)
// pulls its head's 8 alphas per octet via register shuffles. Running-max
// rescale keeps everything in registers -- no scratch buffer, no fence.
__global__ __launch_bounds__(256) void k_flashagg(const u16* __restrict__ hb,
    const int* __restrict__ srcs, const float* __restrict__ eas,
    const int* __restrict__ offs,
    const float* __restrict__ asrc, const float* __restrict__ adst,
    const float* __restrict__ wedot, const float* __restrict__ la,
    const float* __restrict__ bias,
    u16* __restrict__ outb,
    int N, int relu_flag, int self_flag){
  int n = blockIdx.x*4 + (threadIdx.x>>6);
  if (n>=N) return;
  int lane = threadIdx.x&63;
  int hh = lane&7, esub = lane>>3;   // producer role
  int ahh = lane>>3;                 // consumer head
  int c0 = lane*8;                   // consumer channel slot
  int beg = offs[n], end = offs[n+1];
  float wd = wedot[hh];
  float adn = adst[n*8+hh];

  // self-loop alpha (producer role), broadcast to consumer role
  float aselfa = -1e30f;
  if (self_flag){
    float a = asrc[n*8+hh] + adn + la[n]*wd;
    aselfa = a>0.f ? a : 0.2f*a;
  }
  float aself_c = __shfl(aselfa, ahh);

  float m = self_flag ? aself_c : -1e30f;
  float s = 0.f;
  float acc[8] = {};

  for (int p0=beg; p0<end; p0+=8){
    // producer: alpha for edge p0+esub, head hh
    int p = p0 + esub;
    float a = -1e30f;
    if (p < end){
      int sp = srcs[p];
      a = asrc[sp*8+hh] + adn + eas[p]*wd;
      a = a>0.f ? a : 0.2f*a;
    }
    // consumer: this head's alphas for the octet (register-only exchange)
    float av[8];
    #pragma unroll
    for (int e=0;e<8;++e) av[e] = __shfl(a, e*8 + ahh);
    float mo = m;
    #pragma unroll
    for (int e=0;e<8;++e) mo = fmaxf(mo, av[e]);
    float f = __expf(m - mo);      // m==-1e30 first octet -> f=0, acc already 0
    m = mo;
    s *= f;
    #pragma unroll
    for (int j=0;j<8;++j) acc[j] *= f;
    #pragma unroll
    for (int e=0;e<8;++e){
      if (p0 + e < end){
        int se = srcs[p0+e];               // wave-uniform -> scalar load
        float ee = __expf(av[e] - m);
        s += ee;
        bf16x8 v = *(const bf16x8*)(hb + (size_t)se*512 + c0);
        #pragma unroll
        for (int j=0;j<8;++j) acc[j] = fmaf(ee, b2f(v[j]), acc[j]);
      }
    }
  }
  if (self_flag){
    float xs = __expf(aself_c - m);        // aself_c <= m by init
    s += xs;
    bf16x8 v = *(const bf16x8*)(hb + (size_t)n*512 + c0);
    #pragma unroll
    for (int j=0;j<8;++j) acc[j] = fmaf(xs, b2f(v[j]), acc[j]);
  }
  float iv = 1.f/(s + 1e-16f);
  bf16x8 ov;
  #pragma unroll
  for (int j=0;j<8;++j){
    float val = acc[j]*iv + bias[c0+j];
    if (relu_flag) val = fmaxf(val, 0.f);
    ov[j] = (short)f2b(val);
  }
  *(bf16x8*)(outb + (size_t)n*512 + c0) = ov;
}

// column mean over bf16 rows: 512 threads (one per channel), 16 rows/block
__global__ __launch_bounds__(512) void k_colmean(const u16* __restrict__ out2b,
                          float* __restrict__ o, int N, float invN){
  int c = threadIdx.x;
  int n0 = blockIdx.x*16;
  int nend = min(n0+16, N);
  float s = 0.f;
  for (int n=n0;n<nend;++n) s += b2f(out2b[(size_t)n*512 + c]);
  atomicAdd(&o[c], s*invN);
}

extern "C" void kernel_launch(void* const* d_in, const int* in_sizes, int n_in,
                              void* d_out, int out_size, void* d_ws, size_t ws_size,
                              hipStream_t stream){
  const float* x   = (const float*)d_in[0];
  const int* eidx  = (const int*)d_in[1];
  const float* ea  = (const float*)d_in[2];
  const float* W1  = (const float*)d_in[3];
  const float* We1 = (const float*)d_in[4];
  const float* as1 = (const float*)d_in[5];
  const float* ad1 = (const float*)d_in[6];
  const float* ae1 = (const float*)d_in[7];
  const float* b1  = (const float*)d_in[8];
  const float* W2  = (const float*)d_in[9];
  const float* We2 = (const float*)d_in[10];
  const float* as2 = (const float*)d_in[11];
  const float* ad2 = (const float*)d_in[12];
  const float* ae2 = (const float*)d_in[13];
  const float* b2  = (const float*)d_in[14];
  float* outp = (float*)d_out;

  const int FIN = 128, D1 = 512;
  const int N = in_sizes[0]/FIN;
  const int E = in_sizes[1]/2;
  const int* srcA = eidx;
  const int* dstA = eidx + E;

  char* ws = (char*)d_ws;
  size_t o = 0;
  auto alloc = [&](size_t bytes)->void*{
    void* p = ws + o; o = (o + bytes + 255) & ~(size_t)255; return p;
  };
  u16*   hb1   = (u16*)  alloc((size_t)N*D1*2);   // layer1 features, bf16
  u16*   hb2   = (u16*)  alloc((size_t)N*D1*2);   // layer2 features, bf16
  u16*   out1rb= (u16*)  alloc((size_t)N*D1*2);   // relu(layer1 out), bf16
  u16*   out2b = (u16*)  alloc((size_t)N*D1*2);   // layer2 out, bf16
  u16*   xb    = (u16*)  alloc((size_t)N*FIN*2);
  u16*   W1t   = (u16*)  alloc((size_t)D1*FIN*2); // [512][128]
  u16*   W2t   = (u16*)  alloc((size_t)D1*D1*2);  // [512][512]
  int*   srcs  = (int*)  alloc((size_t)E*4);
  float* eas   = (float*)alloc((size_t)E*4);
  int*   offs  = (int*)  alloc((size_t)(N+1)*4);
  size_t zbeg = o;
  int*   cnt   = (int*)  alloc((size_t)N*4);
  int*   fill  = (int*)  alloc((size_t)N*4);
  float* easum = (float*)alloc((size_t)N*4);
  size_t zend = o;
  float* asrc  = (float*)alloc((size_t)N*8*4);
  float* adst  = (float*)alloc((size_t)N*8*4);
  float* la    = (float*)alloc((size_t)N*4);
  float* wedot = (float*)alloc(64);
  (void)ws_size; (void)n_in;

  hipMemsetAsync(ws + zbeg, 0, zend - zbeg, stream);
  hipMemsetAsync(d_out, 0, (size_t)out_size*sizeof(float), stream);

  dim3 b256(256);
  int ge = (E+255)/256;
  int gn4 = (N+3)/4;

  // CSR build + prep (merged kernels)
  k_count   <<<ge, b256, 0, stream>>>(dstA, ea, cnt, easum, E);
  k_scan    <<<1, 1024, 0, stream>>>(cnt, offs, N);
  k_scatter <<<ge, b256, 0, stream>>>(srcA, dstA, ea, offs, fill, srcs, eas, E);
  {
    int nbLoop = (N+511)/512;
    k_prep_small<<<nbLoop+2, 512, 0, stream>>>(cnt, easum, la, N,
                                               We1, ae1, We2, ae2, wedot, nbLoop);
    int total4 = N*FIN/4;
    int nbCast = (total4+255)/256;
    int nbW1 = (FIN/64)*(D1/64);          // 16
    int nbW2 = (D1/64)*(D1/64);           // 64
    k_prep_cast<<<nbCast+nbW1+nbW2, b256, 0, stream>>>(x, xb, total4,
                                                       W1, W1t, W2, W2t, nbCast, nbW1);
  }

  // ---- layer 1 (no self loops) ----
  k_gemm_mfma<<<dim3(D1/128, (N+127)/128), b256, 0, stream>>>(xb, W1t, hb1, N, D1, FIN);
  k_alpha_nodes<<<gn4, b256, 0, stream>>>(hb1, as1, ad1, asrc, adst, N);
  k_flashagg<<<gn4, b256, 0, stream>>>(hb1, srcs, eas, offs, asrc, adst, wedot, la,
                                       b1, out1rb, N, 1, 0);

  // ---- layer 2 (self loops, fill='mean') ----
  k_gemm_mfma<<<dim3(D1/128, (N+127)/128), b256, 0, stream>>>(out1rb, W2t, hb2, N, D1, D1);
  k_alpha_nodes<<<gn4, b256, 0, stream>>>(hb2, as2, ad2, asrc, adst, N);
  k_flashagg<<<gn4, b256, 0, stream>>>(hb2, srcs, eas, offs, asrc, adst, wedot+8, la,
                                       b2, out2b, N, 0, 1);

  // ---- mean over nodes ----
  k_colmean<<<(N+15)/16, 512, 0, stream>>>(out2b, outp, N, 1.0f/(float)N);
}

// Round 8
// 179.781 us; speedup vs baseline: 3.6890x; 1.0432x over previous
//
#include <hip/hip_runtime.h>
#include <hip/hip_bf16.h>

#define HD __device__ __forceinline__
typedef unsigned short u16;
typedef __attribute__((ext_vector_type(8))) short bf16x8;
typedef __attribute__((ext_vector_type(4))) float f32x4;

// round-to-nearest-even fp32 -> bf16 bits
HD u16 f2b(float f){
  unsigned u = __float_as_uint(f);
  unsigned r = (u + 0x7fffu + ((u>>16)&1u)) >> 16;
  return (u16)r;
}
HD float b2f(short s){ return __uint_as_float(((unsigned)(u16)s)<<16); }

// ---------------- CSR build ----------------
__global__ void k_count(const int* __restrict__ dst, const float* __restrict__ ea,
                        int* cnt, float* easum, int E){
  int e = blockIdx.x*blockDim.x + threadIdx.x;
  if (e>=E) return;
  int d = dst[e];
  atomicAdd(&cnt[d],1);
  atomicAdd(&easum[d], ea[e]);
}

// two-level scan, one block
__global__ __launch_bounds__(1024) void k_scan(const int* __restrict__ cnt, int* offs, int N){
  __shared__ int lds[1024];
  const int chunk = (N + 1023)/1024;
  const int b = threadIdx.x*chunk;
  int s = 0;
  for (int i=0;i<chunk;++i){ int idx=b+i; if (idx<N) s += cnt[idx]; }
  lds[threadIdx.x] = s;
  __syncthreads();
  #pragma unroll
  for (int off=1; off<1024; off<<=1){
    int t = (threadIdx.x>=(unsigned)off)? lds[threadIdx.x-off] : 0;
    __syncthreads();
    lds[threadIdx.x] += t;
    __syncthreads();
  }
  int excl = lds[threadIdx.x] - s;
  for (int i=0;i<chunk;++i){
    int idx=b+i;
    if (idx<N){ offs[idx] = excl; excl += cnt[idx]; }
  }
  if (threadIdx.x==1023) offs[N] = lds[1023];
}

__global__ void k_scatter(const int* __restrict__ src, const int* __restrict__ dst,
                          const float* __restrict__ ea, const int* __restrict__ offs,
                          int* fill, int* srcs, float* eas, int E){
  int e = blockIdx.x*blockDim.x + threadIdx.x;
  if (e>=E) return;
  int d = dst[e];
  int p = offs[d] + atomicAdd(&fill[d],1);
  srcs[p] = src[e];
  eas[p]  = ea[e];
}

// merged: loop-attr (blocks [0,nbLoop)) + wedot (blocks nbLoop, nbLoop+1)
__global__ __launch_bounds__(512) void k_prep_small(
    const int* __restrict__ cnt, const float* __restrict__ easum, float* la, int N,
    const float* __restrict__ We1, const float* __restrict__ ae1,
    const float* __restrict__ We2, const float* __restrict__ ae2,
    float* wedot, int nbLoop){
  int bx = blockIdx.x;
  if (bx < nbLoop){
    int n = bx*512 + threadIdx.x;
    if (n<N) la[n] = easum[n] / fmaxf((float)cnt[n], 1.f);
    return;
  }
  int which = bx - nbLoop;
  const float* We = which? We2 : We1;
  const float* ae = which? ae2 : ae1;
  int hh = threadIdx.x>>6, lane = threadIdx.x&63;
  float p = We[hh*64+lane]*ae[hh*64+lane];
  #pragma unroll
  for (int o=32;o;o>>=1) p += __shfl_down(p,o);
  if (lane==0) wedot[which*8+hh] = p;
}

// merged: x cast (blocks [0,nbCast)) + W1 transpose (next nbW1) + W2 transpose
__global__ __launch_bounds__(256) void k_prep_cast(
    const float* __restrict__ x, u16* __restrict__ xb, int total4,
    const float* __restrict__ W1, u16* __restrict__ W1t,
    const float* __restrict__ W2, u16* __restrict__ W2t,
    int nbCast, int nbW1){
  __shared__ float T[64][65];
  int bx = blockIdx.x;
  if (bx < nbCast){
    int i = bx*256 + threadIdx.x;
    if (i<total4){
      float4 v = *(const float4*)(x + (size_t)i*4);
      ushort4 o; o.x=f2b(v.x); o.y=f2b(v.y); o.z=f2b(v.z); o.w=f2b(v.w);
      *(ushort4*)(xb + (size_t)i*4) = o;
    }
    return;
  }
  const float* W; u16* Wt; int K, Nn, t;
  if (bx < nbCast + nbW1){ t = bx - nbCast;        W = W1; Wt = W1t; K = 128; Nn = 512; }
  else                   { t = bx - nbCast - nbW1; W = W2; Wt = W2t; K = 512; Nn = 512; }
  int nt = Nn/64;
  int k0 = (t/nt)*64, n0 = (t%nt)*64;
  #pragma unroll
  for (int i=0;i<16;++i){
    int id = i*256 + threadIdx.x;
    int r = id>>6, c = id&63;
    T[r][c] = W[(size_t)(k0+r)*Nn + n0 + c];
  }
  __syncthreads();
  #pragma unroll
  for (int i=0;i<16;++i){
    int id = i*256 + threadIdx.x;
    int rr = id>>6, cc = id&63;
    Wt[(size_t)(n0+rr)*K + k0 + cc] = f2b(T[cc][rr]);
  }
}

// ---------------- bf16 MFMA GEMM + fused alpha epilogue ----------------
// Cb[M,N] = A[M,K] @ Bt[N,K]^T (bf16 out). Additionally computes
// asrc[row,h] = dot(C[row, h*64:(h+1)*64], a_s[h*64:...]) and likewise adst,
// using the bf16-ROUNDED outputs. Each wave's 64-col span == one head, and
// each (row,head) is produced by exactly one wave -> plain stores, no atomics.
// tile 128x128, BK=32, 256 threads = 4 waves in 2x2 (wave tile 64x64)
__global__ __launch_bounds__(256) void k_gemm_mfma(
    const u16* __restrict__ A, const u16* __restrict__ Bt,
    u16* __restrict__ Cb,
    const float* __restrict__ a_s, const float* __restrict__ a_d,
    float* __restrict__ asrc, float* __restrict__ adst,
    int M, int N, int K){
  __shared__ char lds[256*80];   // A:128 rows, B:128 rows; stride 80B (conflict-free)
  char* As = lds;
  char* Bs = lds + 128*80;
  const int tid = threadIdx.x;
  const int lane = tid & 63, w = tid >> 6;
  const int wr = w >> 1, wc = w & 1;
  const int l15 = lane & 15, l4 = lane >> 4;
  const int m0 = blockIdx.y*128, n0 = blockIdx.x*128;

  f32x4 acc[4][4] = {};
  int aoff[4], boff[4];
  #pragma unroll
  for (int i=0;i<4;++i) aoff[i] = (wr*64 + i*16 + l15)*80 + l4*16;
  #pragma unroll
  for (int j=0;j<4;++j) boff[j] = (wc*64 + j*16 + l15)*80 + l4*16;

  for (int k0=0; k0<K; k0+=32){
    #pragma unroll
    for (int i=0;i<2;++i){
      int cid = tid*2+i;
      int r = cid>>2, c = cid&3;
      int row = m0 + r;
      float4 v = make_float4(0.f,0.f,0.f,0.f);
      if (row < M) v = *(const float4*)(A + (size_t)row*K + k0 + c*8);
      *(float4*)(As + r*80 + c*16) = v;
    }
    #pragma unroll
    for (int i=0;i<2;++i){
      int cid = tid*2+i;
      int r = cid>>2, c = cid&3;
      float4 v = *(const float4*)(Bt + (size_t)(n0+r)*K + k0 + c*8);
      *(float4*)(Bs + r*80 + c*16) = v;
    }
    __syncthreads();
    bf16x8 a[4], b[4];
    #pragma unroll
    for (int i=0;i<4;++i) a[i] = *reinterpret_cast<const bf16x8*>(As + aoff[i]);
    #pragma unroll
    for (int j=0;j<4;++j) b[j] = *reinterpret_cast<const bf16x8*>(Bs + boff[j]);
    #pragma unroll
    for (int i=0;i<4;++i)
      #pragma unroll
      for (int j=0;j<4;++j)
        acc[i][j] = __builtin_amdgcn_mfma_f32_16x16x32_bf16(a[i], b[j], acc[i][j], 0,0,0);
    __syncthreads();
  }

  // epilogue: store bf16 C + per-(row,head) alpha dots
  const int head = (n0>>6) + wc;
  float sv[4][4] = {}, dv[4][4] = {};
  #pragma unroll
  for (int i=0;i<4;++i){
    #pragma unroll
    for (int j=0;j<4;++j){
      int col = n0 + wc*64 + j*16 + l15;
      float asv = a_s[col], adv = a_d[col];
      #pragma unroll
      for (int r=0;r<4;++r){
        int row = m0 + wr*64 + i*16 + l4*4 + r;
        u16 bits = f2b(acc[i][j][r]);
        float valf = b2f((short)bits);
        if (row < M) Cb[(size_t)row*N + col] = bits;
        sv[i][r] = fmaf(valf, asv, sv[i][r]);
        dv[i][r] = fmaf(valf, adv, dv[i][r]);
      }
    }
  }
  #pragma unroll
  for (int i=0;i<4;++i){
    #pragma unroll
    for (int r=0;r<4;++r){
      float s_ = sv[i][r], d_ = dv[i][r];
      #pragma unroll
      for (int mask=1; mask<16; mask<<=1){
        s_ += __shfl_xor(s_, mask);
        d_ += __shfl_xor(d_, mask);
      }
      if (l15==0){
        int row = m0 + wr*64 + i*16 + l4*4 + r;
        if (row < M){ asrc[row*8+head] = s_; adst[row*8+head] = d_; }
      }
    }
  }
}

// ---------------- single-pass online-softmax aggregate, 16-edge rounds -----
// One wave per node. Producer role (hh=lane&7, esub=lane>>3) computes alpha
// for TWO edges (p0+esub, p0+8+esub) -- both gather chains issue together.
// Consumer role (head ahh=lane>>3, channels lane*8..+8) pulls its head's 16
// alphas + the 16 src indices via register shuffles. Running-max rescale
// keeps everything in registers -- no scratch, no fence.
__global__ __launch_bounds__(256) void k_flashagg(const u16* __restrict__ hb,
    const int* __restrict__ srcs, const float* __restrict__ eas,
    const int* __restrict__ offs,
    const float* __restrict__ asrc, const float* __restrict__ adst,
    const float* __restrict__ wedot, const float* __restrict__ la,
    const float* __restrict__ bias,
    u16* __restrict__ outb,
    int N, int relu_flag, int self_flag){
  int n = blockIdx.x*4 + (threadIdx.x>>6);
  if (n>=N) return;
  int lane = threadIdx.x&63;
  int hh = lane&7, esub = lane>>3;   // producer role
  int ahh = lane>>3;                 // consumer head
  int c0 = lane*8;                   // consumer channel slot
  int beg = offs[n], end = offs[n+1];
  float wd = wedot[hh];
  float adn = adst[n*8+hh];

  // self-loop alpha (producer role), broadcast to consumer role
  float aselfa = -1e30f;
  if (self_flag){
    float a = asrc[n*8+hh] + adn + la[n]*wd;
    aselfa = a>0.f ? a : 0.2f*a;
  }
  float aself_c = __shfl(aselfa, ahh);

  float m = self_flag ? aself_c : -1e30f;
  float s = 0.f;
  float acc[8] = {};

  for (int p0=beg; p0<end; p0+=16){
    int pA = p0 + esub, pB = p0 + 8 + esub;
    float aA = -1e30f, aB = -1e30f;
    int sA = 0, sB = 0;
    if (pA < end){
      sA = srcs[pA];
      float eaA = eas[pA];
      float a = asrc[sA*8+hh] + adn + eaA*wd;
      aA = a>0.f ? a : 0.2f*a;
    }
    if (pB < end){
      sB = srcs[pB];
      float eaB = eas[pB];
      float a = asrc[sB*8+hh] + adn + eaB*wd;
      aB = a>0.f ? a : 0.2f*a;
    }
    // consumer: 16 alphas + 16 src indices, register-only exchange
    float av[16]; int se[16];
    #pragma unroll
    for (int e=0;e<8;++e){ av[e]   = __shfl(aA, e*8 + ahh); se[e]   = __shfl(sA, e*8); }
    #pragma unroll
    for (int e=0;e<8;++e){ av[8+e] = __shfl(aB, e*8 + ahh); se[8+e] = __shfl(sB, e*8); }
    float mo = m;
    #pragma unroll
    for (int e=0;e<16;++e) mo = fmaxf(mo, av[e]);
    float f = __expf(m - mo);      // m==-1e30 first round -> f=0, acc already 0
    m = mo;
    s *= f;
    #pragma unroll
    for (int j=0;j<8;++j) acc[j] *= f;
    #pragma unroll
    for (int e=0;e<16;++e){
      if (p0 + e < end){
        float ee = __expf(av[e] - m);
        s += ee;
        bf16x8 v = *(const bf16x8*)(hb + (size_t)se[e]*512 + c0);
        #pragma unroll
        for (int j=0;j<8;++j) acc[j] = fmaf(ee, b2f(v[j]), acc[j]);
      }
    }
  }
  if (self_flag){
    float xs = __expf(aself_c - m);        // aself_c <= m by init
    s += xs;
    bf16x8 v = *(const bf16x8*)(hb + (size_t)n*512 + c0);
    #pragma unroll
    for (int j=0;j<8;++j) acc[j] = fmaf(xs, b2f(v[j]), acc[j]);
  }
  float iv = 1.f/(s + 1e-16f);
  bf16x8 ov;
  #pragma unroll
  for (int j=0;j<8;++j){
    float val = acc[j]*iv + bias[c0+j];
    if (relu_flag) val = fmaxf(val, 0.f);
    ov[j] = (short)f2b(val);
  }
  *(bf16x8*)(outb + (size_t)n*512 + c0) = ov;
}

// column mean over bf16 rows: 512 threads (one per channel), 16 rows/block
__global__ __launch_bounds__(512) void k_colmean(const u16* __restrict__ out2b,
                          float* __restrict__ o, int N, float invN){
  int c = threadIdx.x;
  int n0 = blockIdx.x*16;
  int nend = min(n0+16, N);
  float s = 0.f;
  for (int n=n0;n<nend;++n) s += b2f(out2b[(size_t)n*512 + c]);
  atomicAdd(&o[c], s*invN);
}

extern "C" void kernel_launch(void* const* d_in, const int* in_sizes, int n_in,
                              void* d_out, int out_size, void* d_ws, size_t ws_size,
                              hipStream_t stream){
  const float* x   = (const float*)d_in[0];
  const int* eidx  = (const int*)d_in[1];
  const float* ea  = (const float*)d_in[2];
  const float* W1  = (const float*)d_in[3];
  const float* We1 = (const float*)d_in[4];
  const float* as1 = (const float*)d_in[5];
  const float* ad1 = (const float*)d_in[6];
  const float* ae1 = (const float*)d_in[7];
  const float* b1  = (const float*)d_in[8];
  const float* W2  = (const float*)d_in[9];
  const float* We2 = (const float*)d_in[10];
  const float* as2 = (const float*)d_in[11];
  const float* ad2 = (const float*)d_in[12];
  const float* ae2 = (const float*)d_in[13];
  const float* b2  = (const float*)d_in[14];
  float* outp = (float*)d_out;

  const int FIN = 128, D1 = 512;
  const int N = in_sizes[0]/FIN;
  const int E = in_sizes[1]/2;
  const int* srcA = eidx;
  const int* dstA = eidx + E;

  char* ws = (char*)d_ws;
  size_t o = 0;
  auto alloc = [&](size_t bytes)->void*{
    void* p = ws + o; o = (o + bytes + 255) & ~(size_t)255; return p;
  };
  u16*   hb1   = (u16*)  alloc((size_t)N*D1*2);   // layer1 features, bf16
  u16*   hb2   = (u16*)  alloc((size_t)N*D1*2);   // layer2 features, bf16
  u16*   out1rb= (u16*)  alloc((size_t)N*D1*2);   // relu(layer1 out), bf16
  u16*   out2b = (u16*)  alloc((size_t)N*D1*2);   // layer2 out, bf16
  u16*   xb    = (u16*)  alloc((size_t)N*FIN*2);
  u16*   W1t   = (u16*)  alloc((size_t)D1*FIN*2); // [512][128]
  u16*   W2t   = (u16*)  alloc((size_t)D1*D1*2);  // [512][512]
  int*   srcs  = (int*)  alloc((size_t)E*4);
  float* eas   = (float*)alloc((size_t)E*4);
  int*   offs  = (int*)  alloc((size_t)(N+1)*4);
  size_t zbeg = o;
  int*   cnt   = (int*)  alloc((size_t)N*4);
  int*   fill  = (int*)  alloc((size_t)N*4);
  float* easum = (float*)alloc((size_t)N*4);
  size_t zend = o;
  float* asrc  = (float*)alloc((size_t)N*8*4);
  float* adst  = (float*)alloc((size_t)N*8*4);
  float* la    = (float*)alloc((size_t)N*4);
  float* wedot = (float*)alloc(64);
  (void)ws_size; (void)n_in;

  hipMemsetAsync(ws + zbeg, 0, zend - zbeg, stream);
  hipMemsetAsync(d_out, 0, (size_t)out_size*sizeof(float), stream);

  dim3 b256(256);
  int ge = (E+255)/256;
  int gn4 = (N+3)/4;

  // CSR build + prep (merged kernels)
  k_count   <<<ge, b256, 0, stream>>>(dstA, ea, cnt, easum, E);
  k_scan    <<<1, 1024, 0, stream>>>(cnt, offs, N);
  k_scatter <<<ge, b256, 0, stream>>>(srcA, dstA, ea, offs, fill, srcs, eas, E);
  {
    int nbLoop = (N+511)/512;
    k_prep_small<<<nbLoop+2, 512, 0, stream>>>(cnt, easum, la, N,
                                               We1, ae1, We2, ae2, wedot, nbLoop);
    int total4 = N*FIN/4;
    int nbCast = (total4+255)/256;
    int nbW1 = (FIN/64)*(D1/64);          // 16
    int nbW2 = (D1/64)*(D1/64);           // 64
    k_prep_cast<<<nbCast+nbW1+nbW2, b256, 0, stream>>>(x, xb, total4,
                                                       W1, W1t, W2, W2t, nbCast, nbW1);
  }

  // ---- layer 1 (no self loops); GEMM also emits asrc/adst ----
  k_gemm_mfma<<<dim3(D1/128, (N+127)/128), b256, 0, stream>>>(
      xb, W1t, hb1, as1, ad1, asrc, adst, N, D1, FIN);
  k_flashagg<<<gn4, b256, 0, stream>>>(hb1, srcs, eas, offs, asrc, adst, wedot, la,
                                       b1, out1rb, N, 1, 0);

  // ---- layer 2 (self loops, fill='mean') ----
  k_gemm_mfma<<<dim3(D1/128, (N+127)/128), b256, 0, stream>>>(
      out1rb, W2t, hb2, as2, ad2, asrc, adst, N, D1, D1);
  k_flashagg<<<gn4, b256, 0, stream>>>(hb2, srcs, eas, offs, asrc, adst, wedot+8, la,
                                       b2, out2b, N, 0, 1);

  // ---- mean over nodes ----
  k_colmean<<<(N+15)/16, 512, 0, stream>>>(out2b, outp, N, 1.0f/(float)N);
}

// Round 9
// 175.167 us; speedup vs baseline: 3.7862x; 1.0263x over previous
//
#include <hip/hip_runtime.h>
#include <hip/hip_bf16.h>

#define HD __device__ __forceinline__
typedef unsigned short u16;
typedef __attribute__((ext_vector_type(8))) short bf16x8;
typedef __attribute__((ext_vector_type(4))) float f32x4;

// round-to-nearest-even fp32 -> bf16 bits
HD u16 f2b(float f){
  unsigned u = __float_as_uint(f);
  unsigned r = (u + 0x7fffu + ((u>>16)&1u)) >> 16;
  return (u16)r;
}
HD float b2f(short s){ return __uint_as_float(((unsigned)(u16)s)<<16); }

// ---------------- shared GEMM body ----------------
// Cb[M,N] = A[M,K] @ Bt[N,K]^T (bf16 out) + fused alpha epilogue:
// asrc[row,h]=dot(Cbf16[row,h*64:...],a_s[...]), likewise adst. Each wave's
// 64-col span == one head; each (row,head) made by exactly one wave -> plain
// stores. tile 128x128, BK=32, 256 thr = 4 waves 2x2 (wave tile 64x64).
// AF32: A is fp32, rounded to bf16 in-register during staging (bit-identical
// to a separate cast pass).
template<int AF32>
HD void gemm_body(const void* Ap, const u16* __restrict__ Bt,
                  u16* __restrict__ Cb,
                  const float* __restrict__ a_s, const float* __restrict__ a_d,
                  float* __restrict__ asrc, float* __restrict__ adst,
                  int M, int N, int K, int bidx, int bidy, char* lds){
  char* As = lds;
  char* Bs = lds + 128*80;   // row stride 80B - conflict-free
  const int tid = threadIdx.x;
  const int lane = tid & 63, w = tid >> 6;
  const int wr = w >> 1, wc = w & 1;
  const int l15 = lane & 15, l4 = lane >> 4;
  const int m0 = bidy*128, n0 = bidx*128;

  f32x4 acc[4][4] = {};
  int aoff[4], boff[4];
  #pragma unroll
  for (int i=0;i<4;++i) aoff[i] = (wr*64 + i*16 + l15)*80 + l4*16;
  #pragma unroll
  for (int j=0;j<4;++j) boff[j] = (wc*64 + j*16 + l15)*80 + l4*16;

  for (int k0=0; k0<K; k0+=32){
    #pragma unroll
    for (int i=0;i<2;++i){
      int cid = tid*2+i;
      int r = cid>>2, c = cid&3;
      int row = m0 + r;
      if (AF32){
        const float* A = (const float*)Ap;
        float4 v0 = make_float4(0.f,0.f,0.f,0.f), v1 = v0;
        if (row < M){
          v0 = *(const float4*)(A + (size_t)row*K + k0 + c*8);
          v1 = *(const float4*)(A + (size_t)row*K + k0 + c*8 + 4);
        }
        ushort4 o0, o1;
        o0.x=f2b(v0.x); o0.y=f2b(v0.y); o0.z=f2b(v0.z); o0.w=f2b(v0.w);
        o1.x=f2b(v1.x); o1.y=f2b(v1.y); o1.z=f2b(v1.z); o1.w=f2b(v1.w);
        *(ushort4*)(As + r*80 + c*16)     = o0;
        *(ushort4*)(As + r*80 + c*16 + 8) = o1;
      } else {
        const u16* A = (const u16*)Ap;
        float4 v = make_float4(0.f,0.f,0.f,0.f);
        if (row < M) v = *(const float4*)(A + (size_t)row*K + k0 + c*8);
        *(float4*)(As + r*80 + c*16) = v;
      }
    }
    #pragma unroll
    for (int i=0;i<2;++i){
      int cid = tid*2+i;
      int r = cid>>2, c = cid&3;
      float4 v = *(const float4*)(Bt + (size_t)(n0+r)*K + k0 + c*8);
      *(float4*)(Bs + r*80 + c*16) = v;
    }
    __syncthreads();
    bf16x8 a[4], b[4];
    #pragma unroll
    for (int i=0;i<4;++i) a[i] = *reinterpret_cast<const bf16x8*>(As + aoff[i]);
    #pragma unroll
    for (int j=0;j<4;++j) b[j] = *reinterpret_cast<const bf16x8*>(Bs + boff[j]);
    #pragma unroll
    for (int i=0;i<4;++i)
      #pragma unroll
      for (int j=0;j<4;++j)
        acc[i][j] = __builtin_amdgcn_mfma_f32_16x16x32_bf16(a[i], b[j], acc[i][j], 0,0,0);
    __syncthreads();
  }

  // epilogue: store bf16 C + per-(row,head) alpha dots
  const int head = (n0>>6) + wc;
  float sv[4][4] = {}, dv[4][4] = {};
  #pragma unroll
  for (int i=0;i<4;++i){
    #pragma unroll
    for (int j=0;j<4;++j){
      int col = n0 + wc*64 + j*16 + l15;
      float asv = a_s[col], adv = a_d[col];
      #pragma unroll
      for (int r=0;r<4;++r){
        int row = m0 + wr*64 + i*16 + l4*4 + r;
        u16 bits = f2b(acc[i][j][r]);
        float valf = b2f((short)bits);
        if (row < M) Cb[(size_t)row*N + col] = bits;
        sv[i][r] = fmaf(valf, asv, sv[i][r]);
        dv[i][r] = fmaf(valf, adv, dv[i][r]);
      }
    }
  }
  #pragma unroll
  for (int i=0;i<4;++i){
    #pragma unroll
    for (int r=0;r<4;++r){
      float s_ = sv[i][r], d_ = dv[i][r];
      #pragma unroll
      for (int mask=1; mask<16; mask<<=1){
        s_ += __shfl_xor(s_, mask);
        d_ += __shfl_xor(d_, mask);
      }
      if (l15==0){
        int row = m0 + wr*64 + i*16 + l4*4 + r;
        if (row < M){ asrc[row*8+head] = s_; adst[row*8+head] = d_; }
      }
    }
  }
}

// ---------------- mega kernel A: count | W1t | W2t | wedot ----------------
__global__ __launch_bounds__(256) void k_prepA(
    const int* __restrict__ dst, const float* __restrict__ ea,
    int* cnt, float* easum, int E, int nbCount,
    const float* __restrict__ W1, u16* __restrict__ W1t,
    const float* __restrict__ W2, u16* __restrict__ W2t,
    const float* __restrict__ We1, const float* __restrict__ ae1,
    const float* __restrict__ We2, const float* __restrict__ ae2,
    float* wedot){
  __shared__ float T[64][65];
  int bx = blockIdx.x;
  int tid = threadIdx.x;
  if (bx < nbCount){
    int e = bx*256 + tid;
    if (e<E){
      int d = dst[e];
      atomicAdd(&cnt[d],1);
      atomicAdd(&easum[d], ea[e]);
    }
    return;
  }
  bx -= nbCount;
  if (bx < 16 + 64){
    const float* W; u16* Wt; int K, t;
    if (bx < 16){ t = bx;      W = W1; Wt = W1t; K = 128; }
    else        { t = bx - 16; W = W2; Wt = W2t; K = 512; }
    const int Nn = 512, nt = 8;
    int k0 = (t/nt)*64, n0 = (t%nt)*64;
    #pragma unroll
    for (int i=0;i<16;++i){
      int id = i*256 + tid;
      int r = id>>6, c = id&63;
      T[r][c] = W[(size_t)(k0+r)*Nn + n0 + c];
    }
    __syncthreads();
    #pragma unroll
    for (int i=0;i<16;++i){
      int id = i*256 + tid;
      int rr = id>>6, cc = id&63;
      Wt[(size_t)(n0+rr)*K + k0 + cc] = f2b(T[cc][rr]);
    }
    return;
  }
  // wedot role: 4 blocks; idx=(which<<1)|hgroup; 4 waves = heads hg*4..+4
  int idx = bx - 80;
  int which = idx>>1, hg = idx&1;
  const float* We = which? We2 : We1;
  const float* ae = which? ae2 : ae1;
  int wv = tid>>6, lane = tid&63;
  int head = hg*4 + wv;
  float p = We[head*64+lane]*ae[head*64+lane];
  #pragma unroll
  for (int o=32;o;o>>=1) p += __shfl_down(p,o);
  if (lane==0) wedot[which*8+head] = p;
}

// ---------------- mega kernel B: scan | loop-attr | GEMM1(fp32 A) ----------
__global__ __launch_bounds__(256) void k_prepB(
    const int* __restrict__ cnt, int* offs, int N, int nbLa,
    const float* __restrict__ easum, float* la,
    const float* __restrict__ x, const u16* __restrict__ W1t,
    u16* __restrict__ hb1,
    const float* __restrict__ a_s, const float* __restrict__ a_d,
    float* __restrict__ asrc, float* __restrict__ adst,
    int M, int Nd, int K){
  __shared__ char glds[256*80];
  __shared__ int slds[256];
  int bx = blockIdx.x;
  int tid = threadIdx.x;
  if (bx == 0){
    // 256-thread two-level scan
    const int chunk = (N + 255)/256;
    const int b = tid*chunk;
    int s = 0;
    for (int i=0;i<chunk;++i){ int idx=b+i; if (idx<N) s += cnt[idx]; }
    slds[tid] = s;
    __syncthreads();
    #pragma unroll
    for (int off=1; off<256; off<<=1){
      int t = (tid>=off)? slds[tid-off] : 0;
      __syncthreads();
      slds[tid] += t;
      __syncthreads();
    }
    int excl = slds[tid] - s;
    for (int i=0;i<chunk;++i){
      int idx=b+i;
      if (idx<N){ offs[idx] = excl; excl += cnt[idx]; }
    }
    if (tid==255) offs[N] = slds[255];
    return;
  }
  if (bx < 1 + nbLa){
    int n = (bx-1)*256 + tid;
    if (n<N) la[n] = easum[n] / fmaxf((float)cnt[n], 1.f);
    return;
  }
  int t = bx - 1 - nbLa;
  gemm_body<1>(x, W1t, hb1, a_s, a_d, asrc, adst, M, Nd, K, t%4, t/4, glds);
}

__global__ void k_scatter(const int* __restrict__ src, const int* __restrict__ dst,
                          const float* __restrict__ ea, const int* __restrict__ offs,
                          int* fill, int* srcs, float* eas, int E){
  int e = blockIdx.x*blockDim.x + threadIdx.x;
  if (e>=E) return;
  int d = dst[e];
  int p = offs[d] + atomicAdd(&fill[d],1);
  srcs[p] = src[e];
  eas[p]  = ea[e];
}

// standalone GEMM (bf16 A) for layer 2
__global__ __launch_bounds__(256) void k_gemm_mfma(
    const u16* __restrict__ A, const u16* __restrict__ Bt,
    u16* __restrict__ Cb,
    const float* __restrict__ a_s, const float* __restrict__ a_d,
    float* __restrict__ asrc, float* __restrict__ adst,
    int M, int N, int K){
  __shared__ char lds[256*80];
  gemm_body<0>(A, Bt, Cb, a_s, a_d, asrc, adst, M, N, K,
               blockIdx.x, blockIdx.y, lds);
}

// ---------------- single-pass online-softmax aggregate, 16-edge rounds -----
__global__ __launch_bounds__(256) void k_flashagg(const u16* __restrict__ hb,
    const int* __restrict__ srcs, const float* __restrict__ eas,
    const int* __restrict__ offs,
    const float* __restrict__ asrc, const float* __restrict__ adst,
    const float* __restrict__ wedot, const float* __restrict__ la,
    const float* __restrict__ bias,
    u16* __restrict__ outb,
    int N, int relu_flag, int self_flag){
  int n = blockIdx.x*4 + (threadIdx.x>>6);
  if (n>=N) return;
  int lane = threadIdx.x&63;
  int hh = lane&7, esub = lane>>3;   // producer role
  int ahh = lane>>3;                 // consumer head
  int c0 = lane*8;                   // consumer channel slot
  int beg = offs[n], end = offs[n+1];
  float wd = wedot[hh];
  float adn = adst[n*8+hh];

  float aselfa = -1e30f;
  if (self_flag){
    float a = asrc[n*8+hh] + adn + la[n]*wd;
    aselfa = a>0.f ? a : 0.2f*a;
  }
  float aself_c = __shfl(aselfa, ahh);

  float m = self_flag ? aself_c : -1e30f;
  float s = 0.f;
  float acc[8] = {};

  for (int p0=beg; p0<end; p0+=16){
    int pA = p0 + esub, pB = p0 + 8 + esub;
    float aA = -1e30f, aB = -1e30f;
    int sA = 0, sB = 0;
    if (pA < end){
      sA = srcs[pA];
      float eaA = eas[pA];
      float a = asrc[sA*8+hh] + adn + eaA*wd;
      aA = a>0.f ? a : 0.2f*a;
    }
    if (pB < end){
      sB = srcs[pB];
      float eaB = eas[pB];
      float a = asrc[sB*8+hh] + adn + eaB*wd;
      aB = a>0.f ? a : 0.2f*a;
    }
    float av[16]; int se[16];
    #pragma unroll
    for (int e=0;e<8;++e){ av[e]   = __shfl(aA, e*8 + ahh); se[e]   = __shfl(sA, e*8); }
    #pragma unroll
    for (int e=0;e<8;++e){ av[8+e] = __shfl(aB, e*8 + ahh); se[8+e] = __shfl(sB, e*8); }
    float mo = m;
    #pragma unroll
    for (int e=0;e<16;++e) mo = fmaxf(mo, av[e]);
    float f = __expf(m - mo);
    m = mo;
    s *= f;
    #pragma unroll
    for (int j=0;j<8;++j) acc[j] *= f;
    #pragma unroll
    for (int e=0;e<16;++e){
      if (p0 + e < end){
        float ee = __expf(av[e] - m);
        s += ee;
        bf16x8 v = *(const bf16x8*)(hb + (size_t)se[e]*512 + c0);
        #pragma unroll
        for (int j=0;j<8;++j) acc[j] = fmaf(ee, b2f(v[j]), acc[j]);
      }
    }
  }
  if (self_flag){
    float xs = __expf(aself_c - m);
    s += xs;
    bf16x8 v = *(const bf16x8*)(hb + (size_t)n*512 + c0);
    #pragma unroll
    for (int j=0;j<8;++j) acc[j] = fmaf(xs, b2f(v[j]), acc[j]);
  }
  float iv = 1.f/(s + 1e-16f);
  bf16x8 ov;
  #pragma unroll
  for (int j=0;j<8;++j){
    float val = acc[j]*iv + bias[c0+j];
    if (relu_flag) val = fmaxf(val, 0.f);
    ov[j] = (short)f2b(val);
  }
  *(bf16x8*)(outb + (size_t)n*512 + c0) = ov;
}

// column mean over bf16 rows: 512 threads (one per channel), 16 rows/block
__global__ __launch_bounds__(512) void k_colmean(const u16* __restrict__ out2b,
                          float* __restrict__ o, int N, float invN){
  int c = threadIdx.x;
  int n0 = blockIdx.x*16;
  int nend = min(n0+16, N);
  float s = 0.f;
  for (int n=n0;n<nend;++n) s += b2f(out2b[(size_t)n*512 + c]);
  atomicAdd(&o[c], s*invN);
}

extern "C" void kernel_launch(void* const* d_in, const int* in_sizes, int n_in,
                              void* d_out, int out_size, void* d_ws, size_t ws_size,
                              hipStream_t stream){
  const float* x   = (const float*)d_in[0];
  const int* eidx  = (const int*)d_in[1];
  const float* ea  = (const float*)d_in[2];
  const float* W1  = (const float*)d_in[3];
  const float* We1 = (const float*)d_in[4];
  const float* as1 = (const float*)d_in[5];
  const float* ad1 = (const float*)d_in[6];
  const float* ae1 = (const float*)d_in[7];
  const float* b1  = (const float*)d_in[8];
  const float* W2  = (const float*)d_in[9];
  const float* We2 = (const float*)d_in[10];
  const float* as2 = (const float*)d_in[11];
  const float* ad2 = (const float*)d_in[12];
  const float* ae2 = (const float*)d_in[13];
  const float* b2  = (const float*)d_in[14];
  float* outp = (float*)d_out;

  const int FIN = 128, D1 = 512;
  const int N = in_sizes[0]/FIN;
  const int E = in_sizes[1]/2;
  const int* srcA = eidx;
  const int* dstA = eidx + E;

  char* ws = (char*)d_ws;
  size_t o = 0;
  auto alloc = [&](size_t bytes)->void*{
    void* p = ws + o; o = (o + bytes + 255) & ~(size_t)255; return p;
  };
  u16*   hb1   = (u16*)  alloc((size_t)N*D1*2);   // layer1 features, bf16
  u16*   hb2   = (u16*)  alloc((size_t)N*D1*2);   // layer2 features, bf16
  u16*   out1rb= (u16*)  alloc((size_t)N*D1*2);   // relu(layer1 out), bf16
  u16*   out2b = (u16*)  alloc((size_t)N*D1*2);   // layer2 out, bf16
  u16*   W1t   = (u16*)  alloc((size_t)D1*FIN*2); // [512][128]
  u16*   W2t   = (u16*)  alloc((size_t)D1*D1*2);  // [512][512]
  int*   srcs  = (int*)  alloc((size_t)E*4);
  float* eas   = (float*)alloc((size_t)E*4);
  int*   offs  = (int*)  alloc((size_t)(N+1)*4);
  size_t zbeg = o;
  int*   cnt   = (int*)  alloc((size_t)N*4);
  int*   fill  = (int*)  alloc((size_t)N*4);
  float* easum = (float*)alloc((size_t)N*4);
  size_t zend = o;
  float* asrc  = (float*)alloc((size_t)N*8*4);
  float* adst  = (float*)alloc((size_t)N*8*4);
  float* la    = (float*)alloc((size_t)N*4);
  float* wedot = (float*)alloc(64);
  (void)ws_size; (void)n_in;

  hipMemsetAsync(ws + zbeg, 0, zend - zbeg, stream);
  hipMemsetAsync(d_out, 0, (size_t)out_size*sizeof(float), stream);

  dim3 b256(256);
  int ge = (E+255)/256;          // 625
  int gn4 = (N+3)/4;             // 2500

  // A: count | W1 transpose | W2 transpose | wedot   (all independent)
  int nbCount = ge;
  k_prepA<<<nbCount + 16 + 64 + 4, b256, 0, stream>>>(
      dstA, ea, cnt, easum, E, nbCount,
      W1, W1t, W2, W2t, We1, ae1, We2, ae2, wedot);

  // B: scan | loop-attr | GEMM1 (fp32 A, in-register bf16 round)
  int nbLa = (N+255)/256;        // 40
  int nbG1 = (D1/128)*((N+127)/128);  // 316
  k_prepB<<<1 + nbLa + nbG1, b256, 0, stream>>>(
      cnt, offs, N, nbLa, easum, la,
      x, W1t, hb1, as1, ad1, asrc, adst, N, D1, FIN);

  // C: scatter (needs offs)
  k_scatter<<<ge, b256, 0, stream>>>(srcA, dstA, ea, offs, fill, srcs, eas, E);

  // D: layer-1 flash aggregate
  k_flashagg<<<gn4, b256, 0, stream>>>(hb1, srcs, eas, offs, asrc, adst, wedot, la,
                                       b1, out1rb, N, 1, 0);

  // E: GEMM2 (bf16 A) + alpha epilogue
  k_gemm_mfma<<<dim3(D1/128, (N+127)/128), b256, 0, stream>>>(
      out1rb, W2t, hb2, as2, ad2, asrc, adst, N, D1, D1);

  // F: layer-2 flash aggregate (self loops, fill='mean')
  k_flashagg<<<gn4, b256, 0, stream>>>(hb2, srcs, eas, offs, asrc, adst, wedot+8, la,
                                       b2, out2b, N, 0, 1);

  // G: mean over nodes
  k_colmean<<<(N+15)/16, 512, 0, stream>>>(out2b, outp, N, 1.0f/(float)N);
}